// Round 1
// baseline (249.791 us; speedup 1.0000x reference)
//
#include <hip/hip_runtime.h>
#include <hip/hip_bf16.h>
#include <stdint.h>

// Problem constants
#define BSZ 256
#define HDIM 2048
#define NQ 4096          // Q_SIZE
#define N1 8320          // GEMM1 padded N (65*128): [qkv_half 4096 | gate 4096 | alpha 32 | beta 32 | pad 64]
#define K1 2048
#define N3 2048
#define K3 4096

typedef __attribute__((ext_vector_type(8))) short bf16x8;
typedef __attribute__((ext_vector_type(4))) float f32x4;

__device__ __forceinline__ unsigned short f2bf(float f) {
  union { float f; unsigned u; } v; v.f = f;
  unsigned r = v.u + 0x7fffu + ((v.u >> 16) & 1u);   // RNE
  return (unsigned short)(r >> 16);
}

__device__ __forceinline__ void gload_lds16(const void* g, void* lds_uniform) {
  __builtin_amdgcn_global_load_lds(
      (const __attribute__((address_space(1))) unsigned int*)g,
      (__attribute__((address_space(3))) unsigned int*)lds_uniform, 16, 0, 0);
}

// ---------------- K0: hidden fp32 -> bf16 ----------------
__global__ __launch_bounds__(256) void cvt_kernel(const float* __restrict__ x,
                                                  unsigned short* __restrict__ y) {
  int i = (blockIdx.x * 256 + threadIdx.x) * 8;
  float4 a = *(const float4*)(x + i);
  float4 b = *(const float4*)(x + i + 4);
  ushort4 o0 = { f2bf(a.x), f2bf(a.y), f2bf(a.z), f2bf(a.w) };
  ushort4 o1 = { f2bf(b.x), f2bf(b.y), f2bf(b.z), f2bf(b.w) };
  *(ushort4*)(y + i) = o0;
  *(ushort4*)(y + i + 4) = o1;
}

// ---------------- K1: GEMM1  P = hidden @ [Wqkv_half;Wgate;Walpha;Wbeta]^T ----------------
// 128x128 tile, BK=32, 4 waves (2x2), split-K=2. A16 bf16 via global_load_lds; B fp32->bf16 staged.
__global__ __launch_bounds__(256) void gemm1_kernel(
    const unsigned short* __restrict__ A16,   // [256][2048] bf16
    const float* __restrict__ Wqkv, const float* __restrict__ Wgate,
    const float* __restrict__ Walpha, const float* __restrict__ Wbeta,
    float* __restrict__ P) {                  // [2][256][8320] fp32 partials
  __shared__ unsigned short sA[128 * 32];
  __shared__ unsigned short sB[128 * 32];
  const int tid = threadIdx.x;
  const int lane = tid & 63, wv = tid >> 6;
  const int wr = wv >> 1, wc = wv & 1;
  const int rt = blockIdx.x * 128;
  const int n0 = blockIdx.y * 128;
  const int kbase = blockIdx.z * 1024;

  f32x4 acc[4][4];
#pragma unroll
  for (int i = 0; i < 4; i++)
#pragma unroll
    for (int j = 0; j < 4; j++) { f32x4 z = {0.f, 0.f, 0.f, 0.f}; acc[i][j] = z; }

  for (int ks = 0; ks < 32; ks++) {
    const int k0 = kbase + ks * 32;
    // A: 128 rows x 32 bf16 = 8KB, 8 chunks of 1024B, 2 per wave
#pragma unroll
    for (int it = 0; it < 2; it++) {
      int chunk = (it * 4 + wv) * 1024;
      int f = chunk + lane * 16;
      const char* g = (const char*)A16 + (size_t)(rt + (f >> 6)) * (K1 * 2) + k0 * 2 + (f & 63);
      gload_lds16(g, (char*)sA + chunk);
    }
    // B: 128 rows x 32 fp32 -> bf16
#pragma unroll
    for (int it = 0; it < 4; it++) {
      int flat = it * 256 + tid;            // 0..1023
      int brow = flat >> 3, c4 = flat & 7;
      int n = n0 + brow;
      const float* src;
      if (n < 4096)       src = Wqkv  + (size_t)(4096 + n) * K1;
      else if (n < 8192)  src = Wgate + (size_t)(n - 4096) * K1;
      else if (n < 8224)  src = Walpha + (size_t)(n - 8192) * K1;
      else if (n < 8256)  src = Wbeta + (size_t)(n - 8224) * K1;
      else                src = Walpha;     // dummy pad rows, never consumed
      float4 v = *(const float4*)(src + k0 + c4 * 4);
      ushort4 o = { f2bf(v.x), f2bf(v.y), f2bf(v.z), f2bf(v.w) };
      *(ushort4*)(sB + brow * 32 + c4 * 4) = o;
    }
    __syncthreads();
    bf16x8 aF[4], bF[4];
#pragma unroll
    for (int i = 0; i < 4; i++)
      aF[i] = *(const bf16x8*)(sA + (wr * 64 + i * 16 + (lane & 15)) * 32 + (lane >> 4) * 8);
#pragma unroll
    for (int j = 0; j < 4; j++)
      bF[j] = *(const bf16x8*)(sB + (wc * 64 + j * 16 + (lane & 15)) * 32 + (lane >> 4) * 8);
#pragma unroll
    for (int i = 0; i < 4; i++)
#pragma unroll
      for (int j = 0; j < 4; j++)
        acc[i][j] = __builtin_amdgcn_mfma_f32_16x16x32_bf16(aF[i], bF[j], acc[i][j], 0, 0, 0);
    __syncthreads();
  }
  float* Pz = P + (size_t)blockIdx.z * (BSZ * (size_t)N1);
#pragma unroll
  for (int i = 0; i < 4; i++) {
    int row = rt + wr * 64 + i * 16 + (lane >> 4) * 4;
#pragma unroll
    for (int j = 0; j < 4; j++) {
      int col = n0 + wc * 64 + j * 16 + (lane & 15);
#pragma unroll
      for (int r = 0; r < 4; r++)
        Pz[(size_t)(row + r) * N1 + col] = acc[i][j][r];
    }
  }
}

// ---------------- K2: per-row fused conv + SSM + RMS + gate; writes core bf16 ----------------
__global__ __launch_bounds__(256) void fuse_kernel(
    const float* __restrict__ P,        // [2][256][8320]
    const float* __restrict__ bqkv,     // [8192]
    const float* __restrict__ ck,       // [8192][4]
    const float* __restrict__ cstate,   // [256][4][8192]
    const float* __restrict__ ssa,      // [32]
    const float* __restrict__ dtb,      // [32]
    const float* __restrict__ nw,       // [128]
    const float* __restrict__ sstate,   // [256][32]
    unsigned short* __restrict__ C16) { // [256][4096] bf16
  __shared__ __align__(16) float cb[4096];
  __shared__ float gsum[64];
  __shared__ float ssl[32];
  __shared__ float red[8];
  __shared__ float mw;
  const int b = blockIdx.x, tid = threadIdx.x;
  const float* P0 = P + (size_t)b * N1;
  const float* P1 = P + (size_t)(BSZ + b) * N1;

  if (tid < 64) gsum[tid] = 0.f;
  if (tid == 0) mw = 0.f;
  __syncthreads();
  if (tid < 128) atomicAdd(&mw, nw[tid]);

  // pass 1: core_base (conv) + group sums
#pragma unroll
  for (int it = 0; it < 4; it++) {
    int j = (it * 256 + tid) * 4;
    float4 q0 = *(const float4*)(P0 + j);
    float4 q1 = *(const float4*)(P1 + j);
    float4 bq = *(const float4*)(bqkv + NQ + j);
    float mqx = q0.x + q1.x + bq.x, mqy = q0.y + q1.y + bq.y;
    float mqz = q0.z + q1.z + bq.z, mqw = q0.w + q1.w + bq.w;
    const float* csb = cstate + (size_t)b * 4 * 8192 + NQ + j;
    float4 c1 = *(const float4*)(csb + 1 * 8192);
    float4 c2 = *(const float4*)(csb + 2 * 8192);
    float4 c3 = *(const float4*)(csb + 3 * 8192);
    float4 k0v = *(const float4*)(ck + (size_t)(NQ + j) * 4);
    float4 k1v = *(const float4*)(ck + (size_t)(NQ + j + 1) * 4);
    float4 k2v = *(const float4*)(ck + (size_t)(NQ + j + 2) * 4);
    float4 k3v = *(const float4*)(ck + (size_t)(NQ + j + 3) * 4);
    float4 cbv;
    cbv.x = c1.x * k0v.x + c2.x * k0v.y + c3.x * k0v.z + mqx * k0v.w;
    cbv.y = c1.y * k1v.x + c2.y * k1v.y + c3.y * k1v.z + mqy * k1v.w;
    cbv.z = c1.z * k2v.x + c2.z * k2v.y + c3.z * k2v.z + mqz * k2v.w;
    cbv.w = c1.w * k3v.x + c2.w * k3v.y + c3.w * k3v.z + mqw * k3v.w;
    *(float4*)(cb + j) = cbv;
    float s = cbv.x + cbv.y + cbv.z + cbv.w;
    int g = (j < 2048) ? (j >> 6) : (32 + ((j - 2048) >> 6));
    atomicAdd(&gsum[g], s);
  }
  __syncthreads();

  if (tid < 32) {
    float a  = P0[2 * NQ + tid] + P1[2 * NQ + tid];
    float bc = P0[2 * NQ + 32 + tid] + P1[2 * NQ + 32 + tid];
    float kg = gsum[tid] * (1.f / 64.f);
    float vg = gsum[32 + tid] * (1.f / 64.f);
    float x = a + dtb[tid];
    float sp = fmaxf(x, 0.f) + log1pf(expf(-fabsf(x)));   // stable softplus
    float g = -expf(ssa[tid]) * sp;
    float beta = 1.f / (1.f + expf(-bc));
    float ns = expf(g) * sstate[b * 32 + tid] + beta * vg;
    ssl[tid] = ns * (1.f / (1.f + expf(-kg)));
  }
  __syncthreads();

  // pass 2: core1 = core_base + expanded; sum of squares
  float sq = 0.f;
  float4 c1r[4];
#pragma unroll
  for (int it = 0; it < 4; it++) {
    int j = (it * 256 + tid) * 4;
    float4 v = *(const float4*)(cb + j);
    float sv = ssl[j >> 7];
    v.x += sv; v.y += sv; v.z += sv; v.w += sv;
    c1r[it] = v;
    sq += v.x * v.x + v.y * v.y + v.z * v.z + v.w * v.w;
  }
#pragma unroll
  for (int off = 32; off > 0; off >>= 1) sq += __shfl_down(sq, off, 64);
  if ((tid & 63) == 0) red[tid >> 6] = sq;
  __syncthreads();
  if (tid == 0) {
    float tot = red[0] + red[1] + red[2] + red[3];
    red[4] = rsqrtf(tot * (1.f / 4096.f) + 1e-6f);
    red[5] = mw * (1.f / 128.f);
  }
  __syncthreads();
  float rms = red[4], mwv = red[5];

  // pass 3: apply gate, write bf16
#pragma unroll
  for (int it = 0; it < 4; it++) {
    int j = (it * 256 + tid) * 4;
    float4 g0 = *(const float4*)(P0 + NQ + j);
    float4 g1 = *(const float4*)(P1 + NQ + j);
    float4 v = c1r[it];
    float ox = v.x * rms * mwv * (1.f / (1.f + expf(-(g0.x + g1.x))));
    float oy = v.y * rms * mwv * (1.f / (1.f + expf(-(g0.y + g1.y))));
    float oz = v.z * rms * mwv * (1.f / (1.f + expf(-(g0.z + g1.z))));
    float ow = v.w * rms * mwv * (1.f / (1.f + expf(-(g0.w + g1.w))));
    ushort4 u = { f2bf(ox), f2bf(oy), f2bf(oz), f2bf(ow) };
    *(ushort4*)(C16 + (size_t)b * 4096 + j) = u;
  }
}

// ---------------- K3: GEMM3 out += core @ Wout^T (atomic split-K) ----------------
__global__ __launch_bounds__(256) void gemm3_kernel(
    const unsigned short* __restrict__ A16,  // core [256][4096] bf16
    const float* __restrict__ Wout,          // [2048][4096] fp32
    float* __restrict__ out) {               // [256][2048] fp32 (zeroed)
  __shared__ unsigned short sA[128 * 32];
  __shared__ unsigned short sB[128 * 32];
  const int tid = threadIdx.x;
  const int lane = tid & 63, wv = tid >> 6;
  const int wr = wv >> 1, wc = wv & 1;
  const int rt = blockIdx.x * 128;
  const int n0 = blockIdx.y * 128;
  const int kbase = blockIdx.z * 512;

  f32x4 acc[4][4];
#pragma unroll
  for (int i = 0; i < 4; i++)
#pragma unroll
    for (int j = 0; j < 4; j++) { f32x4 z = {0.f, 0.f, 0.f, 0.f}; acc[i][j] = z; }

  for (int ks = 0; ks < 16; ks++) {
    const int k0 = kbase + ks * 32;
#pragma unroll
    for (int it = 0; it < 2; it++) {
      int chunk = (it * 4 + wv) * 1024;
      int f = chunk + lane * 16;
      const char* g = (const char*)A16 + (size_t)(rt + (f >> 6)) * (K3 * 2) + k0 * 2 + (f & 63);
      gload_lds16(g, (char*)sA + chunk);
    }
#pragma unroll
    for (int it = 0; it < 4; it++) {
      int flat = it * 256 + tid;
      int brow = flat >> 3, c4 = flat & 7;
      const float* src = Wout + (size_t)(n0 + brow) * K3;
      float4 v = *(const float4*)(src + k0 + c4 * 4);
      ushort4 o = { f2bf(v.x), f2bf(v.y), f2bf(v.z), f2bf(v.w) };
      *(ushort4*)(sB + brow * 32 + c4 * 4) = o;
    }
    __syncthreads();
    bf16x8 aF[4], bF[4];
#pragma unroll
    for (int i = 0; i < 4; i++)
      aF[i] = *(const bf16x8*)(sA + (wr * 64 + i * 16 + (lane & 15)) * 32 + (lane >> 4) * 8);
#pragma unroll
    for (int j = 0; j < 4; j++)
      bF[j] = *(const bf16x8*)(sB + (wc * 64 + j * 16 + (lane & 15)) * 32 + (lane >> 4) * 8);
#pragma unroll
    for (int i = 0; i < 4; i++)
#pragma unroll
      for (int j = 0; j < 4; j++)
        acc[i][j] = __builtin_amdgcn_mfma_f32_16x16x32_bf16(aF[i], bF[j], acc[i][j], 0, 0, 0);
    __syncthreads();
  }
#pragma unroll
  for (int i = 0; i < 4; i++) {
    int row = rt + wr * 64 + i * 16 + (lane >> 4) * 4;
#pragma unroll
    for (int j = 0; j < 4; j++) {
      int col = n0 + wc * 64 + j * 16 + (lane & 15);
#pragma unroll
      for (int r = 0; r < 4; r++)
        atomicAdd(&out[(size_t)(row + r) * N3 + col], acc[i][j][r]);
    }
  }
}

extern "C" void kernel_launch(void* const* d_in, const int* in_sizes, int n_in,
                              void* d_out, int out_size, void* d_ws, size_t ws_size,
                              hipStream_t stream) {
  const float* hidden = (const float*)d_in[0];
  const float* Wqkv   = (const float*)d_in[1];
  const float* bqkv   = (const float*)d_in[2];
  const float* Wgate  = (const float*)d_in[3];
  const float* Walpha = (const float*)d_in[4];
  const float* Wbeta  = (const float*)d_in[5];
  const float* Wout   = (const float*)d_in[6];
  const float* ssa    = (const float*)d_in[7];
  const float* dtb    = (const float*)d_in[8];
  const float* nw     = (const float*)d_in[9];
  const float* ck     = (const float*)d_in[10];
  const float* sstate = (const float*)d_in[11];
  const float* cstate = (const float*)d_in[12];
  float* out = (float*)d_out;

  char* ws = (char*)d_ws;
  unsigned short* A16 = (unsigned short*)ws;                              // 1 MB
  float* P = (float*)(ws + (1 << 20));                                    // 2*256*8320*4 = 17,039,360 B
  unsigned short* C16 = (unsigned short*)(ws + (1 << 20) + (size_t)2 * BSZ * N1 * 4); // 2 MB

  hipMemsetAsync(d_out, 0, (size_t)BSZ * N3 * sizeof(float), stream);
  cvt_kernel<<<256, 256, 0, stream>>>(hidden, A16);
  gemm1_kernel<<<dim3(2, 65, 2), 256, 0, stream>>>(A16, Wqkv, Wgate, Walpha, Wbeta, P);
  fuse_kernel<<<256, 256, 0, stream>>>(P, bqkv, ck, cstate, ssa, dtb, nw, sstate, C16);
  gemm3_kernel<<<dim3(2, 16, 8), 256, 0, stream>>>(C16, Wout, out);
}

// Round 2
// 248.199 us; speedup vs baseline: 1.0064x; 1.0064x over previous
//
#include <hip/hip_runtime.h>
#include <hip/hip_bf16.h>
#include <stdint.h>

// Problem constants
#define BSZ 256
#define NQ 4096          // Q_SIZE
#define N1 8320          // GEMM1 padded N (130*64): [qkv_half 4096 | gate 4096 | alpha 32 | beta 32 | pad 64]
#define K1 2048
#define N3 2048
#define K3 4096

typedef __attribute__((ext_vector_type(8))) short bf16x8;
typedef __attribute__((ext_vector_type(4))) float f32x4;

__device__ __forceinline__ unsigned short f2bf(float f) {
  union { float f; unsigned u; } v; v.f = f;
  unsigned r = v.u + 0x7fffu + ((v.u >> 16) & 1u);   // RNE
  return (unsigned short)(r >> 16);
}

__device__ __forceinline__ bf16x8 pack8(float4 a, float4 b) {
  union { bf16x8 v; unsigned short u[8]; } o;
  o.u[0] = f2bf(a.x); o.u[1] = f2bf(a.y); o.u[2] = f2bf(a.z); o.u[3] = f2bf(a.w);
  o.u[4] = f2bf(b.x); o.u[5] = f2bf(b.y); o.u[6] = f2bf(b.z); o.u[7] = f2bf(b.w);
  return o.v;
}

__device__ __forceinline__ void gload_lds16(const void* g, void* lds_uniform) {
  __builtin_amdgcn_global_load_lds(
      (const __attribute__((address_space(1))) unsigned int*)g,
      (__attribute__((address_space(3))) unsigned int*)lds_uniform, 16, 0, 0);
}

// ---------------- K0: hidden fp32 -> bf16 ----------------
__global__ __launch_bounds__(256) void cvt_kernel(const float* __restrict__ x,
                                                  unsigned short* __restrict__ y) {
  int i = (blockIdx.x * 256 + threadIdx.x) * 8;
  float4 a = *(const float4*)(x + i);
  float4 b = *(const float4*)(x + i + 4);
  ushort4 o0 = { f2bf(a.x), f2bf(a.y), f2bf(a.z), f2bf(a.w) };
  ushort4 o1 = { f2bf(b.x), f2bf(b.y), f2bf(b.z), f2bf(b.w) };
  *(ushort4*)(y + i) = o0;
  *(ushort4*)(y + i + 4) = o1;
}

// ---------------- K1: GEMM1  P += hidden @ [Wqkv_half;Wgate;Walpha;Wbeta]^T ----------------
// Tile 128(M)x64(N), BK=32, split-K=2 via atomics. Double-buffered LDS staging.
__global__ __launch_bounds__(256) void gemm1_kernel(
    const unsigned short* __restrict__ A16,   // [256][2048] bf16
    const float* __restrict__ Wqkv, const float* __restrict__ Wgate,
    const float* __restrict__ Walpha, const float* __restrict__ Wbeta,
    float* __restrict__ P) {                  // [256][8320] fp32 (zeroed, atomic)
  __shared__ unsigned short sA[2][128 * 32];
  __shared__ unsigned short sB[2][64 * 32];
  const int tid = threadIdx.x, lane = tid & 63, wv = tid >> 6;
  const int wr = wv >> 1, wc = wv & 1;
  const int rt = blockIdx.x * 128;
  const int n0 = blockIdx.y * 64;
  const int kb = blockIdx.z * 1024;

  // B: thread stages row brow (of 64), 8 floats at column bcol
  const int brow = tid >> 2, bcol = (tid & 3) * 8;
  const float* bsrc;
  {
    int n = n0 + brow;
    const float* s;
    if (n < 4096)       s = Wqkv  + (size_t)(4096 + n) * K1;
    else if (n < 8192)  s = Wgate + (size_t)(n - 4096) * K1;
    else if (n < 8224)  s = Walpha + (size_t)(n - 8192) * K1;
    else if (n < 8256)  s = Wbeta + (size_t)(n - 8224) * K1;
    else                s = Walpha;           // pad rows, never consumed
    bsrc = s + kb + bcol;
  }
  // A: 128 rows x 64B per tile = 8KB; thread covers 16B at byte f = tid*16 (per 4KB half)
  const char* asrc0 = (const char*)(A16 + (size_t)(rt + (tid >> 2)) * K1 + kb) + (tid & 3) * 16;
  const char* asrc1 = asrc0 + (size_t)64 * K1 * 2;

  f32x4 acc[4][2];
#pragma unroll
  for (int i = 0; i < 4; i++)
#pragma unroll
    for (int j = 0; j < 2; j++) { f32x4 z = {0.f, 0.f, 0.f, 0.f}; acc[i][j] = z; }

  float4 pb0, pb1;
  // prologue: stage tile 0 into buffer 0
  gload_lds16(asrc0, (char*)sA[0] + wv * 1024);
  gload_lds16(asrc1, (char*)sA[0] + 4096 + wv * 1024);
  pb0 = *(const float4*)bsrc;
  pb1 = *(const float4*)(bsrc + 4);
  *(bf16x8*)&sB[0][brow * 32 + bcol] = pack8(pb0, pb1);

  for (int ks = 0; ks < 32; ks++) {
    const int cur = ks & 1, nxt = cur ^ 1;
    __syncthreads();                          // buf[cur] staged (DMA drained here too)
    if (ks + 1 < 32) {                        // issue next tile's loads before compute
      gload_lds16(asrc0 + (ks + 1) * 64, (char*)sA[nxt] + wv * 1024);
      gload_lds16(asrc1 + (ks + 1) * 64, (char*)sA[nxt] + 4096 + wv * 1024);
      pb0 = *(const float4*)(bsrc + (ks + 1) * 32);
      pb1 = *(const float4*)(bsrc + (ks + 1) * 32 + 4);
    }
    bf16x8 aF[4], bF[2];
#pragma unroll
    for (int i = 0; i < 4; i++)
      aF[i] = *(const bf16x8*)(&sA[cur][(wr * 64 + i * 16 + (lane & 15)) * 32 + (lane >> 4) * 8]);
#pragma unroll
    for (int j = 0; j < 2; j++)
      bF[j] = *(const bf16x8*)(&sB[cur][(wc * 32 + j * 16 + (lane & 15)) * 32 + (lane >> 4) * 8]);
#pragma unroll
    for (int i = 0; i < 4; i++)
#pragma unroll
      for (int j = 0; j < 2; j++)
        acc[i][j] = __builtin_amdgcn_mfma_f32_16x16x32_bf16(aF[i], bF[j], acc[i][j], 0, 0, 0);
    if (ks + 1 < 32)
      *(bf16x8*)&sB[nxt][brow * 32 + bcol] = pack8(pb0, pb1);
  }

#pragma unroll
  for (int i = 0; i < 4; i++) {
    int row = rt + wr * 64 + i * 16 + (lane >> 4) * 4;
#pragma unroll
    for (int j = 0; j < 2; j++) {
      int col = n0 + wc * 32 + j * 16 + (lane & 15);
#pragma unroll
      for (int r = 0; r < 4; r++)
        atomicAdd(&P[(size_t)(row + r) * N1 + col], acc[i][j][r]);
    }
  }
}

// ---------------- K2: per-row fused conv + SSM + RMS + gate; writes core bf16 ----------------
__global__ __launch_bounds__(512) void fuse_kernel(
    const float* __restrict__ P,        // [256][8320]
    const float* __restrict__ bqkv,     // [8192]
    const float* __restrict__ ck,       // [8192][4]
    const float* __restrict__ cstate,   // [256][4][8192]
    const float* __restrict__ ssa,      // [32]
    const float* __restrict__ dtb,      // [32]
    const float* __restrict__ nw,       // [128]
    const float* __restrict__ sstate,   // [256][32]
    unsigned short* __restrict__ C16) { // [256][4096] bf16
  __shared__ __align__(16) float cb[4096];
  __shared__ float gsum[64];
  __shared__ float ssl[32];
  __shared__ float red[16];
  const int b = blockIdx.x, tid = threadIdx.x;
  const int lane = tid & 63, wv = tid >> 6;
  const float* Pb = P + (size_t)b * N1;

  if (wv == 0) {   // mean(ssm_norm_weight)
    float m = nw[lane] + nw[lane + 64];
#pragma unroll
    for (int off = 32; off; off >>= 1) m += __shfl_down(m, off, 64);
    if (lane == 0) red[8] = m * (1.f / 128.f);
  }

  // pass 1: core_base (conv) + group sums via 16-lane shuffle reduce
#pragma unroll
  for (int it = 0; it < 2; it++) {
    int j = (it * 512 + tid) * 4;
    float4 q  = *(const float4*)(Pb + j);
    float4 bq = *(const float4*)(bqkv + NQ + j);
    float mqx = q.x + bq.x, mqy = q.y + bq.y, mqz = q.z + bq.z, mqw = q.w + bq.w;
    const float* csb = cstate + (size_t)b * 4 * 8192 + NQ + j;
    float4 c1 = *(const float4*)(csb + 8192);
    float4 c2 = *(const float4*)(csb + 16384);
    float4 c3 = *(const float4*)(csb + 24576);
    float4 k0v = *(const float4*)(ck + (size_t)(NQ + j) * 4);
    float4 k1v = *(const float4*)(ck + (size_t)(NQ + j + 1) * 4);
    float4 k2v = *(const float4*)(ck + (size_t)(NQ + j + 2) * 4);
    float4 k3v = *(const float4*)(ck + (size_t)(NQ + j + 3) * 4);
    float4 cbv;
    cbv.x = c1.x * k0v.x + c2.x * k0v.y + c3.x * k0v.z + mqx * k0v.w;
    cbv.y = c1.y * k1v.x + c2.y * k1v.y + c3.y * k1v.z + mqy * k1v.w;
    cbv.z = c1.z * k2v.x + c2.z * k2v.y + c3.z * k2v.z + mqz * k2v.w;
    cbv.w = c1.w * k3v.x + c2.w * k3v.y + c3.w * k3v.z + mqw * k3v.w;
    *(float4*)(cb + j) = cbv;
    float s = cbv.x + cbv.y + cbv.z + cbv.w;
    s += __shfl_xor(s, 1, 64); s += __shfl_xor(s, 2, 64);
    s += __shfl_xor(s, 4, 64); s += __shfl_xor(s, 8, 64);
    if ((lane & 15) == 0) gsum[(it * 512 + tid) >> 4] = s;   // single writer per group
  }
  __syncthreads();

  if (tid < 32) {
    float a  = Pb[8192 + tid];
    float bc = Pb[8224 + tid];
    float kg = gsum[tid] * (1.f / 64.f);
    float vg = gsum[32 + tid] * (1.f / 64.f);
    float x = a + dtb[tid];
    float sp = fmaxf(x, 0.f) + log1pf(expf(-fabsf(x)));   // stable softplus
    float g = -expf(ssa[tid]) * sp;
    float beta = 1.f / (1.f + expf(-bc));
    float ns = expf(g) * sstate[b * 32 + tid] + beta * vg;
    ssl[tid] = ns / (1.f + expf(-kg));
  }
  __syncthreads();

  // pass 2: core1 = core_base + expanded; sum of squares
  float sq = 0.f;
  float4 c1r[2];
#pragma unroll
  for (int it = 0; it < 2; it++) {
    int j = (it * 512 + tid) * 4;
    float4 v = *(const float4*)(cb + j);
    float sv = ssl[j >> 7];
    v.x += sv; v.y += sv; v.z += sv; v.w += sv;
    c1r[it] = v;
    sq += v.x * v.x + v.y * v.y + v.z * v.z + v.w * v.w;
  }
#pragma unroll
  for (int off = 32; off; off >>= 1) sq += __shfl_down(sq, off, 64);
  if (lane == 0) red[wv] = sq;
  __syncthreads();
  if (tid == 0) {
    float t = red[0] + red[1] + red[2] + red[3] + red[4] + red[5] + red[6] + red[7];
    red[9] = rsqrtf(t * (1.f / 4096.f) + 1e-6f);
  }
  __syncthreads();
  float rms = red[9], mwv = red[8];

  // pass 3: apply gate, write bf16
#pragma unroll
  for (int it = 0; it < 2; it++) {
    int j = (it * 512 + tid) * 4;
    float4 g0 = *(const float4*)(Pb + NQ + j);
    float4 v = c1r[it];
    float ox = v.x * rms * mwv / (1.f + expf(-g0.x));
    float oy = v.y * rms * mwv / (1.f + expf(-g0.y));
    float oz = v.z * rms * mwv / (1.f + expf(-g0.z));
    float ow = v.w * rms * mwv / (1.f + expf(-g0.w));
    ushort4 u = { f2bf(ox), f2bf(oy), f2bf(oz), f2bf(ow) };
    *(ushort4*)(C16 + (size_t)b * 4096 + j) = u;
  }
}

// ---------------- K3: GEMM3 out += core @ Wout^T ----------------
// Tile 128(M)x64(N), BK=32, split-K=8 via atomics. Double-buffered LDS staging.
__global__ __launch_bounds__(256) void gemm3_kernel(
    const unsigned short* __restrict__ A16,  // core [256][4096] bf16
    const float* __restrict__ Wout,          // [2048][4096] fp32
    float* __restrict__ out) {               // [256][2048] fp32 (zeroed)
  __shared__ unsigned short sA[2][128 * 32];
  __shared__ unsigned short sB[2][64 * 32];
  const int tid = threadIdx.x, lane = tid & 63, wv = tid >> 6;
  const int wr = wv >> 1, wc = wv & 1;
  const int rt = blockIdx.x * 128;
  const int n0 = blockIdx.y * 64;
  const int kb = blockIdx.z * 512;

  const int brow = tid >> 2, bcol = (tid & 3) * 8;
  const float* bsrc = Wout + (size_t)(n0 + brow) * K3 + kb + bcol;
  const char* asrc0 = (const char*)(A16 + (size_t)(rt + (tid >> 2)) * K3 + kb) + (tid & 3) * 16;
  const char* asrc1 = asrc0 + (size_t)64 * K3 * 2;

  f32x4 acc[4][2];
#pragma unroll
  for (int i = 0; i < 4; i++)
#pragma unroll
    for (int j = 0; j < 2; j++) { f32x4 z = {0.f, 0.f, 0.f, 0.f}; acc[i][j] = z; }

  float4 pb0, pb1;
  gload_lds16(asrc0, (char*)sA[0] + wv * 1024);
  gload_lds16(asrc1, (char*)sA[0] + 4096 + wv * 1024);
  pb0 = *(const float4*)bsrc;
  pb1 = *(const float4*)(bsrc + 4);
  *(bf16x8*)&sB[0][brow * 32 + bcol] = pack8(pb0, pb1);

  for (int ks = 0; ks < 16; ks++) {
    const int cur = ks & 1, nxt = cur ^ 1;
    __syncthreads();
    if (ks + 1 < 16) {
      gload_lds16(asrc0 + (ks + 1) * 64, (char*)sA[nxt] + wv * 1024);
      gload_lds16(asrc1 + (ks + 1) * 64, (char*)sA[nxt] + 4096 + wv * 1024);
      pb0 = *(const float4*)(bsrc + (ks + 1) * 32);
      pb1 = *(const float4*)(bsrc + (ks + 1) * 32 + 4);
    }
    bf16x8 aF[4], bF[2];
#pragma unroll
    for (int i = 0; i < 4; i++)
      aF[i] = *(const bf16x8*)(&sA[cur][(wr * 64 + i * 16 + (lane & 15)) * 32 + (lane >> 4) * 8]);
#pragma unroll
    for (int j = 0; j < 2; j++)
      bF[j] = *(const bf16x8*)(&sB[cur][(wc * 32 + j * 16 + (lane & 15)) * 32 + (lane >> 4) * 8]);
#pragma unroll
    for (int i = 0; i < 4; i++)
#pragma unroll
      for (int j = 0; j < 2; j++)
        acc[i][j] = __builtin_amdgcn_mfma_f32_16x16x32_bf16(aF[i], bF[j], acc[i][j], 0, 0, 0);
    if (ks + 1 < 16)
      *(bf16x8*)&sB[nxt][brow * 32 + bcol] = pack8(pb0, pb1);
  }

#pragma unroll
  for (int i = 0; i < 4; i++) {
    int row = rt + wr * 64 + i * 16 + (lane >> 4) * 4;
#pragma unroll
    for (int j = 0; j < 2; j++) {
      int col = n0 + wc * 32 + j * 16 + (lane & 15);
#pragma unroll
      for (int r = 0; r < 4; r++)
        atomicAdd(&out[(size_t)(row + r) * N3 + col], acc[i][j][r]);
    }
  }
}

extern "C" void kernel_launch(void* const* d_in, const int* in_sizes, int n_in,
                              void* d_out, int out_size, void* d_ws, size_t ws_size,
                              hipStream_t stream) {
  const float* hidden = (const float*)d_in[0];
  const float* Wqkv   = (const float*)d_in[1];
  const float* bqkv   = (const float*)d_in[2];
  const float* Wgate  = (const float*)d_in[3];
  const float* Walpha = (const float*)d_in[4];
  const float* Wbeta  = (const float*)d_in[5];
  const float* Wout   = (const float*)d_in[6];
  const float* ssa    = (const float*)d_in[7];
  const float* dtb    = (const float*)d_in[8];
  const float* nw     = (const float*)d_in[9];
  const float* ck     = (const float*)d_in[10];
  const float* sstate = (const float*)d_in[11];
  const float* cstate = (const float*)d_in[12];
  float* out = (float*)d_out;

  char* ws = (char*)d_ws;
  unsigned short* A16 = (unsigned short*)ws;                              // 1 MB
  float* P = (float*)(ws + (1 << 20));                                    // 256*8320*4 = 8,519,680 B
  unsigned short* C16 = (unsigned short*)(ws + (1 << 20) + 8519680);      // 2 MB

  hipMemsetAsync(d_out, 0, (size_t)BSZ * N3 * sizeof(float), stream);
  hipMemsetAsync(P, 0, (size_t)BSZ * N1 * sizeof(float), stream);
  cvt_kernel<<<256, 256, 0, stream>>>(hidden, A16);
  gemm1_kernel<<<dim3(2, 130, 2), 256, 0, stream>>>(A16, Wqkv, Wgate, Walpha, Wbeta, P);
  fuse_kernel<<<256, 512, 0, stream>>>(P, bqkv, ck, cstate, ssa, dtb, nw, sstate, C16);
  gemm3_kernel<<<dim3(2, 32, 8), 256, 0, stream>>>(C16, Wout, out);
}